// Round 10
// baseline (67.651 us; speedup 1.0000x reference)
//
#include <hip/hip_runtime.h>
#include <math.h>

#define Bb 64
#define Ll 1024
#define Dd 512
#define Aa 512
#define NEG_INF -1e9f

#define LOG2E  1.4426950408889634f
#define LOG2E2 2.8853901617526703f   // 2*log2(e)

typedef float fx4 __attribute__((ext_vector_type(4)));

__device__ __forceinline__ float fast_exp2(float x) { return __builtin_amdgcn_exp2f(x); }
__device__ __forceinline__ float fast_rcp(float x)  { return __builtin_amdgcn_rcpf(x); }

#define TERMS(ACC, KA, KB, Q0, Q1, V0, V1)                                      \
    ACC = fmaf(V0.x, fast_rcp(fast_exp2(fmaf(KA.x, LOG2E2, Q0.x)) + 1.f), ACC); \
    ACC = fmaf(V0.y, fast_rcp(fast_exp2(fmaf(KA.y, LOG2E2, Q0.y)) + 1.f), ACC); \
    ACC = fmaf(V0.z, fast_rcp(fast_exp2(fmaf(KA.z, LOG2E2, Q0.z)) + 1.f), ACC); \
    ACC = fmaf(V0.w, fast_rcp(fast_exp2(fmaf(KA.w, LOG2E2, Q0.w)) + 1.f), ACC); \
    ACC = fmaf(V1.x, fast_rcp(fast_exp2(fmaf(KB.x, LOG2E2, Q1.x)) + 1.f), ACC); \
    ACC = fmaf(V1.y, fast_rcp(fast_exp2(fmaf(KB.y, LOG2E2, Q1.y)) + 1.f), ACC); \
    ACC = fmaf(V1.z, fast_rcp(fast_exp2(fmaf(KB.z, LOG2E2, Q1.z)) + 1.f), ACC); \
    ACC = fmaf(V1.w, fast_rcp(fast_exp2(fmaf(KB.w, LOG2E2, Q1.w)) + 1.f), ACC);

#define RED6(A)                    \
    A += __shfl_xor(A, 32);        \
    A += __shfl_xor(A, 16);        \
    A += __shfl_xor(A, 8);         \
    A += __shfl_xor(A, 4);         \
    A += __shfl_xor(A, 2);         \
    A += __shfl_xor(A, 1);

// ---------------- Node A: q in-block + energy + sigmoid ----------------
// grid (4, 64), 512 thr. Phase 1: all 512 q values (wave-per-row, coalesced
// 1KB W loads, shfl reduce). Phase 2: stream 256 l-rows, R6 pattern.
__global__ __launch_bounds__(512) void k_qenergy(const float* __restrict__ key,
                                                 const float* __restrict__ dh,
                                                 const float* __restrict__ W,
                                                 const float* __restrict__ bias,
                                                 const float* __restrict__ vw,
                                                 const float* __restrict__ vg,
                                                 const float* __restrict__ vb,
                                                 const float* __restrict__ r,
                                                 const float* __restrict__ noise,
                                                 const float* __restrict__ mask,
                                                 float* __restrict__ p) {
    const int b  = blockIdx.y;
    const int lc = blockIdx.x;           // l-chunk of 256 rows
    const int tid = threadIdx.x;
    const int wave = tid >> 6, lane = tid & 63;

    __shared__ float h[Dd];
    __shared__ float qs[Aa];
    __shared__ float vs[Aa];
    __shared__ float redS[8], redT[8];

    h[tid] = dh[(size_t)b * Dd + tid];
    const float vwv = vw[tid];
    {
        float s = vwv * vwv;
        float t = vwv;
        #pragma unroll
        for (int off = 32; off; off >>= 1) {
            s += __shfl_xor(s, off);
            t += __shfl_xor(t, off);
        }
        if (lane == 0) { redS[wave] = s; redT[wave] = t; }
    }
    __syncthreads();

    const float sumsq = redS[0] + redS[1] + redS[2] + redS[3]
                      + redS[4] + redS[5] + redS[6] + redS[7];
    const float sumw  = redT[0] + redT[1] + redT[2] + redT[3]
                      + redT[4] + redT[5] + redT[6] + redT[7];
    const float inv = rsqrtf(sumsq);
    const float g   = vg[0];
    const float g2i = 2.f * g * inv;
    const float ec  = g * inv * sumw + vb[0] + r[0];   // sum(vv) + vbias + r

    // ---- phase 1: q rows; wave w owns rows w*64 .. w*64+63 ----
    {
        const fx4* h4 = (const fx4*)h;
        const fx4 h0 = h4[lane];
        const fx4 h1 = h4[lane + 64];
        #pragma unroll 4
        for (int rr = 0; rr < 64; ++rr) {
            const int a = wave * 64 + rr;
            const fx4* Wr = (const fx4*)(W + (size_t)a * Dd);
            fx4 w0 = Wr[lane];
            fx4 w1 = Wr[lane + 64];
            float acc = w0.x * h0.x;
            acc = fmaf(w0.y, h0.y, acc);
            acc = fmaf(w0.z, h0.z, acc);
            acc = fmaf(w0.w, h0.w, acc);
            acc = fmaf(w1.x, h1.x, acc);
            acc = fmaf(w1.y, h1.y, acc);
            acc = fmaf(w1.z, h1.z, acc);
            acc = fmaf(w1.w, h1.w, acc);
            RED6(acc)
            if (lane == 0) {
                qs[a] = (acc + bias[a]) * LOG2E2;   // pre-scaled
                vs[a] = g2i * vw[a];                // = 2*vv
            }
        }
    }
    __syncthreads();

    // ---- phase 2: energy + sigmoid for 256 l-rows ----
    const fx4* qs4 = (const fx4*)qs;
    const fx4* vs4 = (const fx4*)vs;
    const fx4 q0 = qs4[lane];
    const fx4 q1 = qs4[lane + 64];
    const fx4 v0 = vs4[lane];
    const fx4 v1 = vs4[lane + 64];

    const int lj = lane & 7;
    const int lblk = lc * 256;

    #pragma unroll 1
    for (int it = 0; it < 4; ++it) {
        const int lw0 = lblk + it * 64 + wave * 8;   // this batch's first l
        const int l = lw0 + lj;
        const float mk = mask[(size_t)b * Ll + l];
        const float nz = noise[(size_t)b * Ll + l];
        const float mn = (l == Ll - 1) ? 0.f : mask[(size_t)b * Ll + l + 1];

        const fx4* kp = (const fx4*)(key + ((size_t)b * Ll + lw0) * Aa);
        fx4 ka0 = kp[lane];           fx4 kb0 = kp[lane + 64];
        fx4 ka1 = kp[lane + 128];     fx4 kb1 = kp[lane + 192];
        fx4 ka2 = kp[lane + 256];     fx4 kb2 = kp[lane + 320];
        fx4 ka3 = kp[lane + 384];     fx4 kb3 = kp[lane + 448];
        fx4 ka4 = kp[lane + 512];     fx4 kb4 = kp[lane + 576];
        fx4 ka5 = kp[lane + 640];     fx4 kb5 = kp[lane + 704];
        fx4 ka6 = kp[lane + 768];     fx4 kb6 = kp[lane + 832];
        fx4 ka7 = kp[lane + 896];     fx4 kb7 = kp[lane + 960];
        __builtin_amdgcn_sched_barrier(0);   // loads stay above the compute

        float a0 = 0.f, a1 = 0.f, a2 = 0.f, a3 = 0.f,
              a4 = 0.f, a5 = 0.f, a6 = 0.f, a7 = 0.f;
        TERMS(a0, ka0, kb0, q0, q1, v0, v1)
        TERMS(a1, ka1, kb1, q0, q1, v0, v1)
        TERMS(a2, ka2, kb2, q0, q1, v0, v1)
        TERMS(a3, ka3, kb3, q0, q1, v0, v1)
        TERMS(a4, ka4, kb4, q0, q1, v0, v1)
        TERMS(a5, ka5, kb5, q0, q1, v0, v1)
        TERMS(a6, ka6, kb6, q0, q1, v0, v1)
        TERMS(a7, ka7, kb7, q0, q1, v0, v1)

        RED6(a0) RED6(a1) RED6(a2) RED6(a3) RED6(a4) RED6(a5) RED6(a6) RED6(a7)

        float sel = a0;
        sel = (lj == 1) ? a1 : sel;
        sel = (lj == 2) ? a2 : sel;
        sel = (lj == 3) ? a3 : sel;
        sel = (lj == 4) ? a4 : sel;
        sel = (lj == 5) ? a5 : sel;
        sel = (lj == 6) ? a6 : sel;
        sel = (lj == 7) ? a7 : sel;

        float e = (mk > 0.f) ? (ec - sel) : NEG_INF;
        float z = e + nz;
        float pv = fast_rcp(1.f + fast_exp2(-z * LOG2E));
        float em = mk * (1.f - mn);
        if (em > 0.f) pv = em;
        if (lane < 8) p[(size_t)b * Ll + l] = pv;
        __builtin_amdgcn_sched_barrier(0);   // no cross-batch register inflation
    }
}

// ---------------- Node B: alpha = p * linear_recurrence ----------------
// grid (64), 256 thr. Thread handles 4 consecutive l.
__global__ __launch_bounds__(256) void k_scan256(const float* __restrict__ p,
                                                 const float* __restrict__ prev,
                                                 float* __restrict__ alpha) {
    const int b = blockIdx.x;
    const int tid = threadIdx.x;
    const int wave = tid >> 6, lane = tid & 63;
    __shared__ float pend[4], wA[4], wB[4];

    const float4 pp = ((const float4*)(p + (size_t)b * Ll))[tid];
    const float4 pa = ((const float4*)(prev + (size_t)b * Ll))[tid];

    if (lane == 63) pend[wave] = pp.w;
    __syncthreads();
    float pm1 = __shfl_up(pp.w, 1);
    if (lane == 0) pm1 = (wave == 0) ? 0.f : pend[wave - 1];

    const float a0 = 1.f - pm1;
    const float a1 = 1.f - pp.x;
    const float a2 = 1.f - pp.y;
    const float a3 = 1.f - pp.z;

    float A = a0, Bv = pa.x;
    Bv = fmaf(a1, Bv, pa.y); A *= a1;
    Bv = fmaf(a2, Bv, pa.z); A *= a2;
    Bv = fmaf(a3, Bv, pa.w); A *= a3;

    float Ai = A, Bi = Bv;
    #pragma unroll
    for (int off = 1; off < 64; off <<= 1) {
        float qA = __shfl_up(Ai, off);
        float qB = __shfl_up(Bi, off);
        if (lane >= off) { Bi = fmaf(Ai, qB, Bi); Ai *= qA; }
    }
    float eA = __shfl_up(Ai, 1), eB = __shfl_up(Bi, 1);
    if (lane == 0) { eA = 1.f; eB = 0.f; }
    if (lane == 63) { wA[wave] = Ai; wB[wave] = Bi; }
    __syncthreads();
    float bwe = 0.f;
    for (int w2 = 0; w2 < wave; ++w2) bwe = fmaf(wA[w2], bwe, wB[w2]);
    float x = fmaf(eA, bwe, eB);

    float4 o;
    x = fmaf(a0, x, pa.x); o.x = pp.x * x;
    x = fmaf(a1, x, pa.y); o.y = pp.y * x;
    x = fmaf(a2, x, pa.z); o.z = pp.z * x;
    x = fmaf(a3, x, pa.w); o.w = pp.w * x;
    ((float4*)(alpha + (size_t)b * Ll))[tid] = o;
}

extern "C" void kernel_launch(void* const* d_in, const int* in_sizes, int n_in,
                              void* d_out, int out_size, void* d_ws, size_t ws_size,
                              hipStream_t stream) {
    const float* dh    = (const float*)d_in[0];   // decoder_h [B,D]
    const float* key   = (const float*)d_in[1];   // key [B,L,A]
    // d_in[2] encoder_outputs — unused by the reference
    const float* prev  = (const float*)d_in[3];   // prev_att [B,L]
    const float* noise = (const float*)d_in[4];   // noise [B,L]
    const float* mask  = (const float*)d_in[5];   // mask [B,L]
    const float* W     = (const float*)d_in[6];   // W [A,D]
    const float* bias  = (const float*)d_in[7];   // b [A]
    const float* vw    = (const float*)d_in[8];   // v_weight [1,A]
    const float* vg    = (const float*)d_in[9];   // v_g [1]
    const float* vb    = (const float*)d_in[10];  // v_bias [1]
    const float* r     = (const float*)d_in[11];  // r [1]
    float* out = (float*)d_out;

    float* p = (float*)d_ws;                      // [64][1024] f32

    k_qenergy<<<dim3(4, Bb), 512, 0, stream>>>(key, dh, W, bias, vw, vg, vb, r,
                                               noise, mask, p);
    k_scan256<<<Bb, 256, 0, stream>>>(p, prev, out);
}

// Round 11
// 38.504 us; speedup vs baseline: 1.7570x; 1.7570x over previous
//
#include <hip/hip_runtime.h>
#include <math.h>

#define Bb 64
#define Ll 1024
#define Dd 512
#define Aa 512
#define NEG_INF -1e9f

#define LOG2E  1.4426950408889634f
#define LOG2E2 2.8853901617526703f   // 2*log2(e)

typedef float fx4 __attribute__((ext_vector_type(4)));

__device__ __forceinline__ float fast_exp2(float x) { return __builtin_amdgcn_exp2f(x); }
__device__ __forceinline__ float fast_rcp(float x)  { return __builtin_amdgcn_rcpf(x); }

// ---------------- K1: qb = dh @ W^T + bias;  vv2, scal ----------------
// grid (16, 64), 256 threads. Thread = eighth of one W row (32 rows/block).
__global__ __launch_bounds__(256) void k_qb(const float* __restrict__ dh,
                                            const float* __restrict__ W,
                                            const float* __restrict__ bias,
                                            const float* __restrict__ vw,
                                            const float* __restrict__ vg,
                                            const float* __restrict__ vb,
                                            const float* __restrict__ r,
                                            float* __restrict__ qb,
                                            float* __restrict__ vv2,
                                            float* __restrict__ scal) {
    __shared__ float h[Dd];
    __shared__ float red[4];
    const int b = blockIdx.y;
    const int c = blockIdx.x;            // a-chunk of 32 rows
    const int tid = threadIdx.x;
    const int rr = tid >> 3;             // row within chunk (0..31)
    const int e  = tid & 7;              // eighth of the row

    ((float2*)h)[tid] = ((const float2*)(dh + (size_t)b * Dd))[tid];
    __syncthreads();

    const int arow = c * 32 + rr;
    const float4* Wr = (const float4*)(W + (size_t)arow * Dd + e * 64);
    const float4* h4 = (const float4*)(h + e * 64);
    float acc = 0.f;
    #pragma unroll
    for (int i = 0; i < 16; ++i) {
        float4 wq = Wr[i];
        float4 hv = h4[i];
        acc = fmaf(wq.x, hv.x, acc);
        acc = fmaf(wq.y, hv.y, acc);
        acc = fmaf(wq.z, hv.z, acc);
        acc = fmaf(wq.w, hv.w, acc);
    }
    acc += __shfl_xor(acc, 1);
    acc += __shfl_xor(acc, 2);
    acc += __shfl_xor(acc, 4);
    if (e == 0) qb[(size_t)b * Aa + arow] = acc + bias[arow];

    if (b == 0 && c == 0) {
        const int wave = tid >> 6, lane = tid & 63;
        float w0 = vw[tid], w1 = vw[tid + 256];
        float s = fmaf(w0, w0, w1 * w1);
        #pragma unroll
        for (int off = 32; off; off >>= 1) s += __shfl_xor(s, off);
        if (lane == 0) red[wave] = s;
        __syncthreads();
        float tot = red[0] + red[1] + red[2] + red[3];
        float inv = rsqrtf(tot);
        float g = vg[0];
        float vva0 = g * w0 * inv, vva1 = g * w1 * inv;
        vv2[tid] = 2.f * vva0;
        vv2[tid + 256] = 2.f * vva1;
        float s2 = vva0 + vva1;
        #pragma unroll
        for (int off = 32; off; off >>= 1) s2 += __shfl_xor(s2, off);
        __syncthreads();
        if (lane == 0) red[wave] = s2;
        __syncthreads();
        if (tid == 0)
            scal[0] = red[0] + red[1] + red[2] + red[3] + vb[0] + r[0];
    }
}

// ---------------- K2: p = masked sigmoid(energy + noise) ----------------
// grid (16, 64), 256 threads. Block covers 64 l; each wave: 2 batches x 8 rows.
// (byte-identical to R6's proven kernel)
#define TERMS(ACC, KA, KB, Q0, Q1, V0, V1)                                      \
    ACC = fmaf(V0.x, fast_rcp(fast_exp2(fmaf(KA.x, LOG2E2, Q0.x)) + 1.f), ACC); \
    ACC = fmaf(V0.y, fast_rcp(fast_exp2(fmaf(KA.y, LOG2E2, Q0.y)) + 1.f), ACC); \
    ACC = fmaf(V0.z, fast_rcp(fast_exp2(fmaf(KA.z, LOG2E2, Q0.z)) + 1.f), ACC); \
    ACC = fmaf(V0.w, fast_rcp(fast_exp2(fmaf(KA.w, LOG2E2, Q0.w)) + 1.f), ACC); \
    ACC = fmaf(V1.x, fast_rcp(fast_exp2(fmaf(KB.x, LOG2E2, Q1.x)) + 1.f), ACC); \
    ACC = fmaf(V1.y, fast_rcp(fast_exp2(fmaf(KB.y, LOG2E2, Q1.y)) + 1.f), ACC); \
    ACC = fmaf(V1.z, fast_rcp(fast_exp2(fmaf(KB.z, LOG2E2, Q1.z)) + 1.f), ACC); \
    ACC = fmaf(V1.w, fast_rcp(fast_exp2(fmaf(KB.w, LOG2E2, Q1.w)) + 1.f), ACC);

#define RED6(A)                    \
    A += __shfl_xor(A, 32);        \
    A += __shfl_xor(A, 16);        \
    A += __shfl_xor(A, 8);         \
    A += __shfl_xor(A, 4);         \
    A += __shfl_xor(A, 2);         \
    A += __shfl_xor(A, 1);

__global__ __launch_bounds__(256) void k_energy(const float* __restrict__ key,
                                                const float* __restrict__ noise,
                                                const float* __restrict__ mask,
                                                const float* __restrict__ qb,
                                                const float* __restrict__ vv2,
                                                const float* __restrict__ scal,
                                                float* __restrict__ p) {
    const int b = blockIdx.y;
    const int tid = threadIdx.x;
    const int wave = tid >> 6, lane = tid & 63;
    const int lblk = blockIdx.x * 64;                // block's first l (64 rows)

    const fx4* qb4 = (const fx4*)(qb + (size_t)b * Aa);
    fx4 q0 = qb4[lane];
    fx4 q1 = qb4[lane + 64];
    const fx4* v4 = (const fx4*)vv2;
    const fx4 v0 = v4[lane];
    const fx4 v1 = v4[lane + 64];
    const float ec = scal[0];
    q0 *= LOG2E2;
    q1 *= LOG2E2;

    const int lj = lane & 7;

    #pragma unroll 1
    for (int it = 0; it < 2; ++it) {
        const int lw0 = lblk + it * 32 + wave * 8;   // this batch's first l
        const int l = lw0 + lj;
        const float mk = mask[(size_t)b * Ll + l];
        const float nz = noise[(size_t)b * Ll + l];
        const float mn = (l == Ll - 1) ? 0.f : mask[(size_t)b * Ll + l + 1];

        const fx4* kp = (const fx4*)(key + ((size_t)b * Ll + lw0) * Aa);  // row = 128 fx4
        fx4 ka0 = kp[lane];           fx4 kb0 = kp[lane + 64];
        fx4 ka1 = kp[lane + 128];     fx4 kb1 = kp[lane + 192];
        fx4 ka2 = kp[lane + 256];     fx4 kb2 = kp[lane + 320];
        fx4 ka3 = kp[lane + 384];     fx4 kb3 = kp[lane + 448];
        fx4 ka4 = kp[lane + 512];     fx4 kb4 = kp[lane + 576];
        fx4 ka5 = kp[lane + 640];     fx4 kb5 = kp[lane + 704];
        fx4 ka6 = kp[lane + 768];     fx4 kb6 = kp[lane + 832];
        fx4 ka7 = kp[lane + 896];     fx4 kb7 = kp[lane + 960];
        __builtin_amdgcn_sched_barrier(0);   // loads stay above the compute

        float a0 = 0.f, a1 = 0.f, a2 = 0.f, a3 = 0.f, a4 = 0.f, a5 = 0.f, a6 = 0.f, a7 = 0.f;
        TERMS(a0, ka0, kb0, q0, q1, v0, v1)
        TERMS(a1, ka1, kb1, q0, q1, v0, v1)
        TERMS(a2, ka2, kb2, q0, q1, v0, v1)
        TERMS(a3, ka3, kb3, q0, q1, v0, v1)
        TERMS(a4, ka4, kb4, q0, q1, v0, v1)
        TERMS(a5, ka5, kb5, q0, q1, v0, v1)
        TERMS(a6, ka6, kb6, q0, q1, v0, v1)
        TERMS(a7, ka7, kb7, q0, q1, v0, v1)

        RED6(a0) RED6(a1) RED6(a2) RED6(a3) RED6(a4) RED6(a5) RED6(a6) RED6(a7)

        float sel = a0;
        sel = (lj == 1) ? a1 : sel;
        sel = (lj == 2) ? a2 : sel;
        sel = (lj == 3) ? a3 : sel;
        sel = (lj == 4) ? a4 : sel;
        sel = (lj == 5) ? a5 : sel;
        sel = (lj == 6) ? a6 : sel;
        sel = (lj == 7) ? a7 : sel;

        float e = (mk > 0.f) ? (ec - sel) : NEG_INF;
        float z = e + nz;
        float pv = fast_rcp(1.f + fast_exp2(-z * LOG2E));
        float em = mk * (1.f - mn);
        if (em > 0.f) pv = em;
        if (lane < 8) p[(size_t)b * Ll + l] = pv;
        __builtin_amdgcn_sched_barrier(0);   // no cross-batch register inflation
    }
}

// ---------------- K3: alpha = p * linear_recurrence ----------------
// grid (64), 256 thr. Thread handles 4 consecutive l. (validated in R10)
__global__ __launch_bounds__(256) void k_scan256(const float* __restrict__ p,
                                                 const float* __restrict__ prev,
                                                 float* __restrict__ alpha) {
    const int b = blockIdx.x;
    const int tid = threadIdx.x;
    const int wave = tid >> 6, lane = tid & 63;
    __shared__ float pend[4], wA[4], wB[4];

    const float4 pp = ((const float4*)(p + (size_t)b * Ll))[tid];
    const float4 pa = ((const float4*)(prev + (size_t)b * Ll))[tid];

    if (lane == 63) pend[wave] = pp.w;
    __syncthreads();
    float pm1 = __shfl_up(pp.w, 1);
    if (lane == 0) pm1 = (wave == 0) ? 0.f : pend[wave - 1];

    const float a0 = 1.f - pm1;
    const float a1 = 1.f - pp.x;
    const float a2 = 1.f - pp.y;
    const float a3 = 1.f - pp.z;

    float A = a0, Bv = pa.x;
    Bv = fmaf(a1, Bv, pa.y); A *= a1;
    Bv = fmaf(a2, Bv, pa.z); A *= a2;
    Bv = fmaf(a3, Bv, pa.w); A *= a3;

    float Ai = A, Bi = Bv;
    #pragma unroll
    for (int off = 1; off < 64; off <<= 1) {
        float qA = __shfl_up(Ai, off);
        float qB = __shfl_up(Bi, off);
        if (lane >= off) { Bi = fmaf(Ai, qB, Bi); Ai *= qA; }
    }
    float eA = __shfl_up(Ai, 1), eB = __shfl_up(Bi, 1);
    if (lane == 0) { eA = 1.f; eB = 0.f; }
    if (lane == 63) { wA[wave] = Ai; wB[wave] = Bi; }
    __syncthreads();
    float bwe = 0.f;
    for (int w2 = 0; w2 < wave; ++w2) bwe = fmaf(wA[w2], bwe, wB[w2]);
    float x = fmaf(eA, bwe, eB);

    float4 o;
    x = fmaf(a0, x, pa.x); o.x = pp.x * x;
    x = fmaf(a1, x, pa.y); o.y = pp.y * x;
    x = fmaf(a2, x, pa.z); o.z = pp.z * x;
    x = fmaf(a3, x, pa.w); o.w = pp.w * x;
    ((float4*)(alpha + (size_t)b * Ll))[tid] = o;
}

extern "C" void kernel_launch(void* const* d_in, const int* in_sizes, int n_in,
                              void* d_out, int out_size, void* d_ws, size_t ws_size,
                              hipStream_t stream) {
    const float* dh    = (const float*)d_in[0];   // decoder_h [B,D]
    const float* key   = (const float*)d_in[1];   // key [B,L,A]
    // d_in[2] encoder_outputs — unused by the reference
    const float* prev  = (const float*)d_in[3];   // prev_att [B,L]
    const float* noise = (const float*)d_in[4];   // noise [B,L]
    const float* mask  = (const float*)d_in[5];   // mask [B,L]
    const float* W     = (const float*)d_in[6];   // W [A,D]
    const float* bias  = (const float*)d_in[7];   // b [A]
    const float* vw    = (const float*)d_in[8];   // v_weight [1,A]
    const float* vg    = (const float*)d_in[9];   // v_g [1]
    const float* vb    = (const float*)d_in[10];  // v_bias [1]
    const float* r     = (const float*)d_in[11];  // r [1]
    float* out = (float*)d_out;

    float* ws   = (float*)d_ws;
    float* vv2  = ws;                        // 512 floats
    float* scal = ws + Aa;                   // 1 float (padded to 1024)
    float* qb   = ws + 1024;                 // 64*512
    float* p    = ws + 1024 + Bb * Aa;       // 64*1024

    k_qb<<<dim3(16, Bb), 256, 0, stream>>>(dh, W, bias, vw, vg, vb, r, qb, vv2, scal);
    k_energy<<<dim3(Ll / 64, Bb), 256, 0, stream>>>(key, noise, mask, qb, vv2, scal, p);
    k_scan256<<<Bb, 256, 0, stream>>>(p, prev, out);
}